// Round 2
// baseline (1208.126 us; speedup 1.0000x reference)
//
#include <hip/hip_runtime.h>
#include <stdint.h>

typedef __attribute__((ext_vector_type(8))) short short8;
typedef __attribute__((ext_vector_type(4))) short short4v;
typedef __attribute__((ext_vector_type(4))) float floatx4;

#define LDQ 136   // Q LDS row stride: 128 + 8 bf16 pad (272B rows, 16B aligned)
#define LDC 132   // cos/sin LDS row stride in floats (528B, 16B aligned)

__device__ __forceinline__ uint16_t f32_to_bf16(float f) {
    uint32_t u = __builtin_bit_cast(uint32_t, f);
    u += 0x7FFFu + ((u >> 16) & 1u);   // RTNE
    return (uint16_t)(u >> 16);
}

__device__ __forceinline__ floatx4 mfma16x16x16_bf16(short4v a, short4v b, floatx4 c) {
#if __has_builtin(__builtin_amdgcn_mfma_f32_16x16x16bf16_1k)
    return __builtin_amdgcn_mfma_f32_16x16x16bf16_1k(a, b, c, 0, 0, 0);
#else
    floatx4 d;
    asm volatile("v_mfma_f32_16x16x16_bf16 %0, %1, %2, %3"
                 : "=v"(d) : "v"(a), "v"(b), "v"(c));
    return d;
#endif
}

// ---------------- Kernel 1: Householder Q, one wave per column ----------------
__global__ __launch_bounds__(256) void hh_q_kernel(const float* __restrict__ vs,
                                                   uint16_t* __restrict__ Qrm,
                                                   uint16_t* __restrict__ Qt) {
    __shared__ float vsl[64 * 128];   // 32 KB
    int tid = threadIdx.x;
    const float4* vsv = (const float4*)vs;
    float4* vslv = (float4*)vsl;
#pragma unroll
    for (int i = 0; i < 8; ++i) vslv[tid + 256 * i] = vsv[tid + 256 * i];
    __syncthreads();

    int wave = tid >> 6, lane = tid & 63;
    int col = blockIdx.x * 4 + wave;          // 32 blocks * 4 waves = 128 cols
    float x0 = (lane == col) ? 1.f : 0.f;
    float x1 = (lane + 64 == col) ? 1.f : 0.f;
    for (int k = 0; k < 64; ++k) {
        float v0 = vsl[k * 128 + lane];
        float v1 = vsl[k * 128 + 64 + lane];
        float d  = v0 * x0 + v1 * x1;
        float vn = v0 * v0 + v1 * v1;
#pragma unroll
        for (int m = 1; m < 64; m <<= 1) {
            d  += __shfl_xor(d, m, 64);
            vn += __shfl_xor(vn, m, 64);
        }
        float sfac = 2.f / (vn + 1e-8f) * d;
        x0 -= sfac * v0;
        x1 -= sfac * v1;
    }
    Qrm[lane * 128 + col]        = f32_to_bf16(x0);
    Qrm[(lane + 64) * 128 + col] = f32_to_bf16(x1);
    Qt[col * 128 + lane]         = f32_to_bf16(x0);   // Qt[a][b] = Q[b][a]
    Qt[col * 128 + lane + 64]    = f32_to_bf16(x1);
}

// ---------------- Kernel 2: fused (x @ Q^T) -> RoPE -> (@ Q) ----------------
// One block = one (b,s16) group of 16 s-rows; 8 waves x 4 tiles (2h x 2t).
// cos/sin staged ONCE per block in LDS (fixes the round-1 L2 re-read storm).
// Swapped-operand GEMM1: acc[nt][r] = C1[m=x][d=16nt+4g+r] (lane owns s-row x).
// Lane d-residency {4g+r mod 16} == B-frag layout of mfma 16x16x16 -> GEMM2
// (out^T = Q^T P^T) straight from regs: no shuffle, no scratch, no 2nd barrier.
// GEMM2 A-operand = Qt rows from GLOBAL (32 KB, L2-hot; proven in 244us kernel).
__global__ __launch_bounds__(512, 6) void rope_rot_kernel(
    const float* __restrict__ qin, const float* __restrict__ kin,
    const float* __restrict__ cosp, const float* __restrict__ sinp,
    const uint16_t* __restrict__ Qrm, const uint16_t* __restrict__ Qt,
    float* __restrict__ outp) {

    __shared__ uint16_t Qlds[128 * LDQ];            // 34816 B  Q row-major
    __shared__ __align__(16) float cslds[2][16 * LDC];  // 16896 B  cos,sin f32
    // total 51712 B -> 3 blocks/CU (155 KB), 24 waves/CU

    int tid = threadIdx.x;
    int bs = blockIdx.x;                 // 1024 blocks = b*256 + s16
    int b = bs >> 8, s16 = bs & 255;

    {   // stage Q (coalesced 16B chunks)
        const short8* qg = (const short8*)Qrm;
#pragma unroll
        for (int i = 0; i < 4; ++i) {
            int e8 = tid + i * 512;          // 2048 chunks of 8 bf16
            int row = e8 >> 4;
            int col = (e8 & 15) * 8;
            *(short8*)&Qlds[row * LDQ + col] = qg[e8];
        }
        // stage cos/sin: 512 float4 each, one per thread
        long gbase = ((long)(b * 4096 + s16 * 16)) * 128;
        int row = tid >> 5, c4 = (tid & 31) * 4;
        *(float4*)&cslds[0][row * LDC + c4] = *(const float4*)(cosp + gbase + row * 128 + c4);
        *(float4*)&cslds[1][row * LDC + c4] = *(const float4*)(sinp + gbase + row * 128 + c4);
    }
    __syncthreads();   // the ONLY barrier

    int wave = tid >> 6, lane = tid & 63;
    int x = lane & 15, g = lane >> 4;

    const float* cbase = &cslds[0][x * LDC + 4 * g];
    const float* sbase = &cslds[1][x * LDC + 4 * g];

#pragma unroll 1
    for (int l = 0; l < 4; ++l) {            // 2 h * 2 tensors per wave
        int h = wave * 2 + (l >> 1);
        int t = l & 1;
        long rowbase = ((long)(b * 16 + h)) * 4096 + s16 * 16;
        const float* src  = t ? kin : qin;
        const float* arow = src + (rowbase + x) * 128 + 8 * g;

        floatx4 zero4 = {0.f, 0.f, 0.f, 0.f};
        floatx4 acc[8];
#pragma unroll
        for (int nt = 0; nt < 8; ++nt) acc[nt] = zero4;

        // ---- GEMM1 (swapped): acc[nt][r] = sum_k q[x][k]*Q[16nt+4g+r][k] ----
#pragma unroll
        for (int kt = 0; kt < 4; ++kt) {
            floatx4 a0 = *(const floatx4*)(arow + kt * 32);
            floatx4 a1 = *(const floatx4*)(arow + kt * 32 + 4);
            short8 af;
#pragma unroll
            for (int j = 0; j < 4; ++j) {
                af[j]     = (short)f32_to_bf16(a0[j]);
                af[j + 4] = (short)f32_to_bf16(a1[j]);
            }
#pragma unroll
            for (int nt = 0; nt < 8; ++nt) {
                short8 qf = *(const short8*)&Qlds[(nt * 16 + x) * LDQ + kt * 32 + 8 * g];
                acc[nt] = __builtin_amdgcn_mfma_f32_16x16x32_bf16(qf, af, acc[nt], 0, 0, 0);
            }
        }

        // ---- RoPE in-register (cos/sin from LDS), pack K=16 B-fragments ----
        short4v pb[8];
#pragma unroll
        for (int nt = 0; nt < 4; ++nt) {
            floatx4 cl = *(const floatx4*)(cbase + nt * 16);
            floatx4 ch = *(const floatx4*)(cbase + (nt + 4) * 16);
            floatx4 sl = *(const floatx4*)(sbase + nt * 16);
            floatx4 sh = *(const floatx4*)(sbase + (nt + 4) * 16);
            short4v lo, hi;
#pragma unroll
            for (int r = 0; r < 4; ++r) {
                float vlo = acc[nt][r] * cl[r] - acc[nt + 4][r] * sl[r];
                float vhi = acc[nt + 4][r] * ch[r] + acc[nt][r] * sh[r];
                lo[r] = (short)f32_to_bf16(vlo);
                hi[r] = (short)f32_to_bf16(vhi);
            }
            pb[nt] = lo;
            pb[nt + 4] = hi;
        }

        // ---- GEMM2: out^T = Q^T P^T via 8x8 K=16 MFMAs, P straight from regs.
        //      A-frag = Qt rows from global (L2-hot 32 KB, shared by all CUs) ----
        floatx4 acc2[8];
#pragma unroll
        for (int nt = 0; nt < 8; ++nt) acc2[nt] = zero4;
#pragma unroll
        for (int ntk = 0; ntk < 8; ++ntk) {
#pragma unroll
            for (int nte = 0; nte < 8; ++nte) {
                short4v a4 = *(const short4v*)&Qt[(nte * 16 + x) * 128 + ntk * 16 + 4 * g];
                acc2[nte] = mfma16x16x16_bf16(a4, pb[ntk], acc2[nte]);
            }
        }

        // ---- float4 stores: lane holds out[m=x][e=16*nte+4g..+3] ----
        float* obase = outp + (long)t * 33554432L + (rowbase + x) * 128 + 4 * g;
#pragma unroll
        for (int nte = 0; nte < 8; ++nte) {
            *(floatx4*)(obase + nte * 16) = acc2[nte];
        }
    }
}

extern "C" void kernel_launch(void* const* d_in, const int* in_sizes, int n_in,
                              void* d_out, int out_size, void* d_ws, size_t ws_size,
                              hipStream_t stream) {
    const float* q   = (const float*)d_in[0];
    const float* k   = (const float*)d_in[1];
    const float* cs  = (const float*)d_in[2];
    const float* sn  = (const float*)d_in[3];
    const float* vs  = (const float*)d_in[4];
    uint16_t* Qrm = (uint16_t*)d_ws;           // 128*128 bf16
    uint16_t* Qt  = Qrm + 128 * 128;           // transposed copy

    hh_q_kernel<<<32, 256, 0, stream>>>(vs, Qrm, Qt);
    // 1024 blocks (one per (b,s16) group) * 512 threads; cos/sin staged once
    // per block in LDS; 3 blocks/CU (51.7 KB LDS), zero main-loop barriers.
    rope_rot_kernel<<<1024, 512, 0, stream>>>(q, k, cs, sn, Qrm, Qt, (float*)d_out);
}

// Round 3
// 1182.997 us; speedup vs baseline: 1.0212x; 1.0212x over previous
//
#include <hip/hip_runtime.h>
#include <stdint.h>

typedef __attribute__((ext_vector_type(8))) short short8;
typedef __attribute__((ext_vector_type(4))) short short4v;
typedef __attribute__((ext_vector_type(4))) float floatx4;

#define LDQ 132   // Q LDS row stride (bf16): 128+4 pad; word-uniform banks for
                  // both the staging writes and the (2x+4g+j) read pattern

__device__ __forceinline__ uint16_t f32_to_bf16(float f) {
    uint32_t u = __builtin_bit_cast(uint32_t, f);
    u += 0x7FFFu + ((u >> 16) & 1u);   // RTNE
    return (uint16_t)(u >> 16);
}

__device__ __forceinline__ floatx4 mfma16x16x16_bf16(short4v a, short4v b, floatx4 c) {
#if __has_builtin(__builtin_amdgcn_mfma_f32_16x16x16bf16_1k)
    return __builtin_amdgcn_mfma_f32_16x16x16bf16_1k(a, b, c, 0, 0, 0);
#else
    floatx4 d;
    asm volatile("v_mfma_f32_16x16x16_bf16 %0, %1, %2, %3"
                 : "=v"(d) : "v"(a), "v"(b), "v"(c));
    return d;
#endif
}

// ---------------- Kernel 1: Householder Q, one wave per column ----------------
__global__ __launch_bounds__(256) void hh_q_kernel(const float* __restrict__ vs,
                                                   uint16_t* __restrict__ Qrm,
                                                   uint16_t* __restrict__ Qt) {
    __shared__ float vsl[64 * 128];   // 32 KB
    int tid = threadIdx.x;
    const float4* vsv = (const float4*)vs;
    float4* vslv = (float4*)vsl;
#pragma unroll
    for (int i = 0; i < 8; ++i) vslv[tid + 256 * i] = vsv[tid + 256 * i];
    __syncthreads();

    int wave = tid >> 6, lane = tid & 63;
    int col = blockIdx.x * 4 + wave;          // 32 blocks * 4 waves = 128 cols
    float x0 = (lane == col) ? 1.f : 0.f;
    float x1 = (lane + 64 == col) ? 1.f : 0.f;
    for (int k = 0; k < 64; ++k) {
        float v0 = vsl[k * 128 + lane];
        float v1 = vsl[k * 128 + 64 + lane];
        float d  = v0 * x0 + v1 * x1;
        float vn = v0 * v0 + v1 * v1;
#pragma unroll
        for (int m = 1; m < 64; m <<= 1) {
            d  += __shfl_xor(d, m, 64);
            vn += __shfl_xor(vn, m, 64);
        }
        float sfac = 2.f / (vn + 1e-8f) * d;
        x0 -= sfac * v0;
        x1 -= sfac * v1;
    }
    Qrm[lane * 128 + col]        = f32_to_bf16(x0);
    Qrm[(lane + 64) * 128 + col] = f32_to_bf16(x1);
    Qt[col * 128 + lane]         = f32_to_bf16(x0);   // Qt[a][b] = Q[b][a]
    Qt[col * 128 + lane + 64]    = f32_to_bf16(x1);
}

// ---------------- Kernel 2: fused (x @ Q^T) -> RoPE -> (@ Q) ----------------
// Block = (b, s16, h-quad), 256 threads / 4 waves; wave w owns h = hq*4+w and
// loops t in {q,k}. Only Q lives in LDS (33.8 KB -> 4 blocks/CU, 16 waves/CU).
// cos/sin read from global (unique 17 MB, L3-resident; tile L1-temporal over t).
// Swapped-operand GEMM1: acc[nt][r] = C1[m=x][d=16nt+4g+r] (lane owns s-row x).
// Lane d-residency == B-frag layout of mfma 16x16x16 -> GEMM2 (out^T = Q^T P^T)
// straight from regs: no shuffle, no scratch, no second barrier.
// Register budget: cap 128 via launch_bounds(256,4); live demand ~100 -> NO
// spills (rounds 1-2 regression was scratch traffic from caps 128/80).
__global__ __launch_bounds__(256, 4) void rope_rot_kernel(
    const float* __restrict__ qin, const float* __restrict__ kin,
    const float* __restrict__ cosp, const float* __restrict__ sinp,
    const uint16_t* __restrict__ Qrm, const uint16_t* __restrict__ Qt,
    float* __restrict__ outp) {

    __shared__ uint16_t Qlds[128 * LDQ];   // 33792 B

    int tid = threadIdx.x;
    {   // stage Q: 2048 16B chunks, coalesced, bank-uniform
        const short8* qg = (const short8*)Qrm;
#pragma unroll
        for (int i = 0; i < 8; ++i) {
            int e8 = tid + i * 256;
            int row = e8 >> 4;
            int col = (e8 & 15) * 8;
            *(short8*)&Qlds[row * LDQ + col] = qg[e8];
        }
    }
    __syncthreads();   // the ONLY barrier

    int bidx = blockIdx.x;                 // 4096 = b(4) * s16(256) * hq(4)
    int hq  = bidx & 3;
    int s16 = (bidx >> 2) & 255;
    int b   = bidx >> 10;

    int wave = tid >> 6, lane = tid & 63;
    int x = lane & 15, g = lane >> 4;
    int h = hq * 4 + wave;

    long rowbase = ((long)(b * 16 + h)) * 4096 + s16 * 16;
    long csoff = ((long)(b * 4096 + s16 * 16 + x)) * 128 + 4 * g;
    const float* cbase = cosp + csoff;     // L1/L2-hot across the two t-iters
    const float* sbase = sinp + csoff;

#pragma unroll 1
    for (int t = 0; t < 2; ++t) {
        const float* src  = t ? kin : qin;
        const float* arow = src + (rowbase + x) * 128 + 8 * g;

        floatx4 zero4 = {0.f, 0.f, 0.f, 0.f};
        floatx4 acc[8];
#pragma unroll
        for (int nt = 0; nt < 8; ++nt) acc[nt] = zero4;

        // ---- GEMM1 (swapped): acc[nt][r] = sum_k q[x][k]*Q[16nt+4g+r][k] ----
#pragma unroll
        for (int kt = 0; kt < 4; ++kt) {
            floatx4 a0 = *(const floatx4*)(arow + kt * 32);
            floatx4 a1 = *(const floatx4*)(arow + kt * 32 + 4);
            short8 af;
#pragma unroll
            for (int j = 0; j < 4; ++j) {
                af[j]     = (short)f32_to_bf16(a0[j]);
                af[j + 4] = (short)f32_to_bf16(a1[j]);
            }
#pragma unroll
            for (int nt = 0; nt < 8; ++nt) {
                short8 qf = *(const short8*)&Qlds[(nt * 16 + x) * LDQ + kt * 32 + 8 * g];
                acc[nt] = __builtin_amdgcn_mfma_f32_16x16x32_bf16(qf, af, acc[nt], 0, 0, 0);
            }
        }

        // ---- RoPE in-register (cos/sin from global), pack K=16 B-frags ----
        short4v pb[8];
#pragma unroll
        for (int nt = 0; nt < 4; ++nt) {
            floatx4 cl = *(const floatx4*)(cbase + nt * 16);
            floatx4 ch = *(const floatx4*)(cbase + (nt + 4) * 16);
            floatx4 sl = *(const floatx4*)(sbase + nt * 16);
            floatx4 sh = *(const floatx4*)(sbase + (nt + 4) * 16);
            short4v lo, hi;
#pragma unroll
            for (int r = 0; r < 4; ++r) {
                float vlo = acc[nt][r] * cl[r] - acc[nt + 4][r] * sl[r];
                float vhi = acc[nt + 4][r] * ch[r] + acc[nt][r] * sh[r];
                lo[r] = (short)f32_to_bf16(vlo);
                hi[r] = (short)f32_to_bf16(vhi);
            }
            pb[nt] = lo;
            pb[nt + 4] = hi;
        }

        // ---- GEMM2: out^T = Q^T P^T, 8x8 K=16 MFMAs, P straight from regs.
        //      A-frag = Qt rows from global (32 KB, L2-resident chip-wide) ----
        floatx4 acc2[8];
#pragma unroll
        for (int nt = 0; nt < 8; ++nt) acc2[nt] = zero4;
#pragma unroll
        for (int ntk = 0; ntk < 8; ++ntk) {
#pragma unroll
            for (int nte = 0; nte < 8; ++nte) {
                short4v a4 = *(const short4v*)&Qt[(nte * 16 + x) * 128 + ntk * 16 + 4 * g];
                acc2[nte] = mfma16x16x16_bf16(a4, pb[ntk], acc2[nte]);
            }
        }

        // ---- nontemporal float4 stores: lane holds out[m=x][16*nte+4g..+3] ----
        float* obase = outp + (long)t * 33554432L + (rowbase + x) * 128 + 4 * g;
#pragma unroll
        for (int nte = 0; nte < 8; ++nte) {
#if __has_builtin(__builtin_nontemporal_store)
            __builtin_nontemporal_store(acc2[nte], (floatx4*)(obase + nte * 16));
#else
            *(floatx4*)(obase + nte * 16) = acc2[nte];
#endif
        }
    }
}

extern "C" void kernel_launch(void* const* d_in, const int* in_sizes, int n_in,
                              void* d_out, int out_size, void* d_ws, size_t ws_size,
                              hipStream_t stream) {
    const float* q   = (const float*)d_in[0];
    const float* k   = (const float*)d_in[1];
    const float* cs  = (const float*)d_in[2];
    const float* sn  = (const float*)d_in[3];
    const float* vs  = (const float*)d_in[4];
    uint16_t* Qrm = (uint16_t*)d_ws;           // 128*128 bf16
    uint16_t* Qt  = Qrm + 128 * 128;           // transposed copy

    hh_q_kernel<<<32, 256, 0, stream>>>(vs, Qrm, Qt);
    // 4096 blocks (b, s16, h-quad) * 256 threads; Q staged once per block;
    // 33.8 KB LDS -> 4 blocks/CU = 16 waves/CU; VGPR cap 128 >= demand -> no
    // scratch spills; zero main-loop barriers.
    rope_rot_kernel<<<4096, 256, 0, stream>>>(q, k, cs, sn, Qrm, Qt, (float*)d_out);
}

// Round 4
// 649.306 us; speedup vs baseline: 1.8606x; 1.8219x over previous
//
#include <hip/hip_runtime.h>
#include <stdint.h>

typedef __attribute__((ext_vector_type(8))) short short8;
typedef __attribute__((ext_vector_type(4))) short short4v;
typedef __attribute__((ext_vector_type(4))) float floatx4;

#define LDQ 132   // Q LDS row stride (bf16): 128+4 pad

__device__ __forceinline__ uint16_t f32_to_bf16(float f) {
    uint32_t u = __builtin_bit_cast(uint32_t, f);
    u += 0x7FFFu + ((u >> 16) & 1u);   // RTNE
    return (uint16_t)(u >> 16);
}

__device__ __forceinline__ floatx4 mfma16x16x16_bf16(short4v a, short4v b, floatx4 c) {
#if __has_builtin(__builtin_amdgcn_mfma_f32_16x16x16bf16_1k)
    return __builtin_amdgcn_mfma_f32_16x16x16bf16_1k(a, b, c, 0, 0, 0);
#else
    floatx4 d;
    asm volatile("v_mfma_f32_16x16x16_bf16 %0, %1, %2, %3"
                 : "=v"(d) : "v"(a), "v"(b), "v"(c));
    return d;
#endif
}

// ---------------- Kernel 1: Householder Q, one wave per column ----------------
__global__ __launch_bounds__(256) void hh_q_kernel(const float* __restrict__ vs,
                                                   uint16_t* __restrict__ Qrm,
                                                   uint16_t* __restrict__ Qt) {
    __shared__ float vsl[64 * 128];   // 32 KB
    int tid = threadIdx.x;
    const float4* vsv = (const float4*)vs;
    float4* vslv = (float4*)vsl;
#pragma unroll
    for (int i = 0; i < 8; ++i) vslv[tid + 256 * i] = vsv[tid + 256 * i];
    __syncthreads();

    int wave = tid >> 6, lane = tid & 63;
    int col = blockIdx.x * 4 + wave;          // 32 blocks * 4 waves = 128 cols
    float x0 = (lane == col) ? 1.f : 0.f;
    float x1 = (lane + 64 == col) ? 1.f : 0.f;
    for (int k = 0; k < 64; ++k) {
        float v0 = vsl[k * 128 + lane];
        float v1 = vsl[k * 128 + 64 + lane];
        float d  = v0 * x0 + v1 * x1;
        float vn = v0 * v0 + v1 * v1;
#pragma unroll
        for (int m = 1; m < 64; m <<= 1) {
            d  += __shfl_xor(d, m, 64);
            vn += __shfl_xor(vn, m, 64);
        }
        float sfac = 2.f / (vn + 1e-8f) * d;
        x0 -= sfac * v0;
        x1 -= sfac * v1;
    }
    Qrm[lane * 128 + col]        = f32_to_bf16(x0);
    Qrm[(lane + 64) * 128 + col] = f32_to_bf16(x1);
    Qt[col * 128 + lane]         = f32_to_bf16(x0);   // Qt[a][b] = Q[b][a]
    Qt[col * 128 + lane + 64]    = f32_to_bf16(x1);
}

// ---------------- Kernel 2: fused (x @ Q^T) -> RoPE -> (@ Q) ----------------
// R3 dataflow (correctness-proven) with the three convicted traffic bugs fixed:
//  1. NO nontemporal stores (R3: nt + partial-line scatter => W = 5x output).
//  2. NO min-waves launch bound (R2: cap 80 => VGPR 40 => scratch storm).
//     LDS 33.8 KB -> 4 blocks/CU = 16 waves; VGPRs up to 128 are free.
//  3. XCD-swizzled blockIdx: the 4 hq-blocks sharing a cos/sin tile (and
//     consecutive s16) colocate on one XCD L2 (R1/R3: scattered sharers =>
//     ~1 GB of cos/sin re-fetch across 8 non-coherent L2s).
// Swapped-operand GEMM1: acc[nt][r] = C1[m=x][d=16nt+4g+r] (lane owns s-row x).
// Lane d-residency == B-frag layout of mfma 16x16x16 -> GEMM2 (out^T = Q^T P^T)
// straight from regs: no shuffle, no scratch, no second barrier.
__global__ __launch_bounds__(256) void rope_rot_kernel(
    const float* __restrict__ qin, const float* __restrict__ kin,
    const float* __restrict__ cosp, const float* __restrict__ sinp,
    const uint16_t* __restrict__ Qrm, const uint16_t* __restrict__ Qt,
    float* __restrict__ outp) {

    __shared__ uint16_t Qlds[128 * LDQ];   // 33792 B

    int tid = threadIdx.x;
    {   // stage Q: 2048 16B chunks, coalesced
        const short8* qg = (const short8*)Qrm;
#pragma unroll
        for (int i = 0; i < 8; ++i) {
            int e8 = tid + i * 256;
            int row = e8 >> 4;
            int col = (e8 & 15) * 8;
            *(short8*)&Qlds[row * LDQ + col] = qg[e8];
        }
    }
    __syncthreads();   // the ONLY barrier

    // bijective XCD swizzle (4096 % 8 == 0): chunk of 512 consecutive wgids
    // per XCD; hq is in the low bits so all 4 sharers of a cos/sin tile land
    // on the same XCD, with s16 locality along the chunk.
    int wgid = (blockIdx.x & 7) * 512 + (blockIdx.x >> 3);
    int hq  = wgid & 3;
    int s16 = (wgid >> 2) & 255;
    int b   = wgid >> 10;

    int wave = tid >> 6, lane = tid & 63;
    int x = lane & 15, g = lane >> 4;
    int h = hq * 4 + wave;

    long rowbase = ((long)(b * 16 + h)) * 4096 + s16 * 16;
    long csoff = ((long)(b * 4096 + s16 * 16 + x)) * 128 + 4 * g;
    const float* cbase = cosp + csoff;     // XCD-L2/L1-hot across t and hq
    const float* sbase = sinp + csoff;

#pragma unroll 1
    for (int t = 0; t < 2; ++t) {
        const float* src  = t ? kin : qin;
        const float* arow = src + (rowbase + x) * 128 + 8 * g;

        floatx4 zero4 = {0.f, 0.f, 0.f, 0.f};
        floatx4 acc[8];
#pragma unroll
        for (int nt = 0; nt < 8; ++nt) acc[nt] = zero4;

        // ---- GEMM1 (swapped): acc[nt][r] = sum_k q[x][k]*Q[16nt+4g+r][k] ----
#pragma unroll
        for (int kt = 0; kt < 4; ++kt) {
            floatx4 a0 = *(const floatx4*)(arow + kt * 32);
            floatx4 a1 = *(const floatx4*)(arow + kt * 32 + 4);
            short8 af;
#pragma unroll
            for (int j = 0; j < 4; ++j) {
                af[j]     = (short)f32_to_bf16(a0[j]);
                af[j + 4] = (short)f32_to_bf16(a1[j]);
            }
#pragma unroll
            for (int nt = 0; nt < 8; ++nt) {
                short8 qf = *(const short8*)&Qlds[(nt * 16 + x) * LDQ + kt * 32 + 8 * g];
                acc[nt] = __builtin_amdgcn_mfma_f32_16x16x32_bf16(qf, af, acc[nt], 0, 0, 0);
            }
        }

        // ---- RoPE in-register (cos/sin from global, XCD-hot), K=16 B-frags ----
        short4v pb[8];
#pragma unroll
        for (int nt = 0; nt < 4; ++nt) {
            floatx4 cl = *(const floatx4*)(cbase + nt * 16);
            floatx4 ch = *(const floatx4*)(cbase + (nt + 4) * 16);
            floatx4 sl = *(const floatx4*)(sbase + nt * 16);
            floatx4 sh = *(const floatx4*)(sbase + (nt + 4) * 16);
            short4v lo, hi;
#pragma unroll
            for (int r = 0; r < 4; ++r) {
                float vlo = acc[nt][r] * cl[r] - acc[nt + 4][r] * sl[r];
                float vhi = acc[nt + 4][r] * ch[r] + acc[nt][r] * sh[r];
                lo[r] = (short)f32_to_bf16(vlo);
                hi[r] = (short)f32_to_bf16(vhi);
            }
            pb[nt] = lo;
            pb[nt + 4] = hi;
        }

        // ---- GEMM2: out^T = Q^T P^T, 8x8 K=16 MFMAs, P straight from regs.
        //      A-frag = Qt rows from global (32 KB, L2-resident chip-wide) ----
        floatx4 acc2[8];
#pragma unroll
        for (int nt = 0; nt < 8; ++nt) acc2[nt] = zero4;
#pragma unroll
        for (int ntk = 0; ntk < 8; ++ntk) {
#pragma unroll
            for (int nte = 0; nte < 8; ++nte) {
                short4v a4 = *(const short4v*)&Qt[(nte * 16 + x) * 128 + ntk * 16 + 4 * g];
                acc2[nte] = mfma16x16x16_bf16(a4, pb[ntk], acc2[nte]);
            }
        }

        // ---- plain float4 stores; nte pairs (0,1),(2,3).. complete each
        //      128B line in two adjacent instructions (L2 write-merge) ----
        float* obase = outp + (long)t * 33554432L + (rowbase + x) * 128 + 4 * g;
#pragma unroll
        for (int nte = 0; nte < 8; ++nte) {
            *(floatx4*)(obase + nte * 16) = acc2[nte];
        }
    }
}

extern "C" void kernel_launch(void* const* d_in, const int* in_sizes, int n_in,
                              void* d_out, int out_size, void* d_ws, size_t ws_size,
                              hipStream_t stream) {
    const float* q   = (const float*)d_in[0];
    const float* k   = (const float*)d_in[1];
    const float* cs  = (const float*)d_in[2];
    const float* sn  = (const float*)d_in[3];
    const float* vs  = (const float*)d_in[4];
    uint16_t* Qrm = (uint16_t*)d_ws;           // 128*128 bf16
    uint16_t* Qt  = Qrm + 128 * 128;           // transposed copy

    hh_q_kernel<<<32, 256, 0, stream>>>(vs, Qrm, Qt);
    // 4096 blocks (XCD-swizzled (b,s16,hq)) * 256 threads; Q staged per block;
    // 33.8 KB LDS -> 4 blocks/CU = 16 waves/CU; no VGPR cap; plain stores.
    rope_rot_kernel<<<4096, 256, 0, stream>>>(q, k, cs, sn, Qrm, Qt, (float*)d_out);
}